// Round 9
// baseline (434.201 us; speedup 1.0000x reference)
//
#include <hip/hip_runtime.h>

#define N_NODES 8192
#define IN_F 256
#define OUT_F 128
#define ALPHA 0.5f
#define JC 4
#define KCHUNK 2048            // N_NODES / JC
#define RK 128                 // k-window per round
#define ROUNDS 16              // KCHUNK / RK

using short8 = __attribute__((ext_vector_type(8))) short;
using f32x4  = __attribute__((ext_vector_type(4))) float;

__device__ __forceinline__ unsigned int f2bf(float f){
  unsigned int u = __float_as_uint(f);
  u += 0x7fffu + ((u >> 16) & 1u);   // RNE
  return u >> 16;
}
__device__ __forceinline__ float bf2f(short s){
  return __uint_as_float(((unsigned int)(unsigned short)s) << 16);
}
__device__ __forceinline__ void gll16(const void* g, void* l){
  __builtin_amdgcn_global_load_lds(
      (const __attribute__((address_space(1))) void*)g,
      (__attribute__((address_space(3))) void*)l, 16, 0, 0);
}

// ---------------- K0: fused  h = x@W  ->  {f1, f2, P(bf16 frag-major)} -----
__global__ __launch_bounds__(256) void k_hfp(const float* __restrict__ x,
                                             const float* __restrict__ W,
                                             const float* __restrict__ a,
                                             unsigned short* __restrict__ P,
                                             float* __restrict__ f1,
                                             float* __restrict__ f2){
  __shared__ float xs[16*IN_F];            // 16 KB; reused as hs[16][132]
  const int tid = threadIdx.x;
  const int bx = blockIdx.x;
  const int r0 = bx * 16;
  const float4* xg = (const float4*)(x + (size_t)r0*IN_F);
  float4* xl = (float4*)xs;
  #pragma unroll
  for(int i=0;i<4;i++) xl[tid + i*256] = xg[tid + i*256];
  __syncthreads();
  const int wave = tid >> 6, lane = tid & 63;
  float2 acc[4];
  #pragma unroll
  for(int j=0;j<4;j++){ acc[j].x = 0.f; acc[j].y = 0.f; }
  const float2* Wp = (const float2*)W;
  for(int k4=0;k4<IN_F;k4+=4){
    float4 xq[4];
    #pragma unroll
    for(int j=0;j<4;j++) xq[j] = *(const float4*)&xs[(wave*4+j)*IN_F + k4];
    #pragma unroll
    for(int kk=0;kk<4;kk++){
      float2 wv = Wp[(size_t)(k4+kk)*64 + lane];
      #pragma unroll
      for(int j=0;j<4;j++){
        float xv = kk==0?xq[j].x : kk==1?xq[j].y : kk==2?xq[j].z : xq[j].w;
        acc[j].x += xv*wv.x; acc[j].y += xv*wv.y;
      }
    }
  }
  // ---- f1 = h@a1, f2 = h@a2 from fp32 accumulators ----
  float2 av1 = ((const float2*)a)[lane];
  float2 av2 = ((const float2*)(a + OUT_F))[lane];
  #pragma unroll
  for(int j=0;j<4;j++){
    float s1 = acc[j].x*av1.x + acc[j].y*av1.y;
    float s2 = acc[j].x*av2.x + acc[j].y*av2.y;
    #pragma unroll
    for(int off=32; off; off>>=1){
      s1 += __shfl_down(s1, off);
      s2 += __shfl_down(s2, off);
    }
    if(lane == 0){ f1[r0 + wave*4 + j] = s1; f2[r0 + wave*4 + j] = s2; }
  }
  // ---- pack bf16 fragment-major into P via LDS re-stage ----
  // P short idx ((kb*8+c)*64 + q*16 + n)*8 + t = bf16(h[kb*32+q*8+t][c*16+n])
  __syncthreads();                         // all waves done reading xs
  #pragma unroll
  for(int j=0;j<4;j++) *(float2*)&xs[(wave*4+j)*132 + lane*2] = acc[j];
  __syncthreads();
  const int kb = bx >> 1, half = bx & 1;   // this block = rows [r0, r0+16) = half of kb's 32
  const int c = tid >> 5, ql = (tid >> 4) & 1, n = tid & 15;
  short8 v;
  #pragma unroll
  for(int t=0;t<8;t++) v[t] = (short)f2bf(xs[(ql*8+t)*132 + c*16 + n]);
  *(short8*)(P + ((size_t)((kb*8 + c)*64 + half*32 + ql*16 + n))*8) = v;
}

// ---------------- K1: DMA-pipelined fused masked-exp + attn@h --------------
// grid (JC=4, 128) x 256 thr, 1 block/CU, LDS 136 KB.
// RK=128: per-round HBM budget (32KB/CU at ~10.25 B/cyc = ~3200 cyc) far
// exceeds HBM latency (~900 cyc), so vmcnt(16) at the round top waits for
// DMAs issued a full round earlier -> zero steady-state stall (round-8's
// RK=64 had a ~400cyc stall/round: round shorter than latency).
// Per round: 16 global_load_lds (8 adj: 2 rows x 512B each; 8 B: 1KB linear)
// -> vmcnt(16) -> s_barrier -> compute (4 substeps: exp from adj granules +
// 16 MFMA) -> lgkmcnt(0) -> s_barrier. No vmcnt(0) in the loop.
// adj granule swizzle (32B granules, low-3-bit XOR): stored g of row rl
// holds global (g&8)|((g&7)^(rl&7)); reader inverts with m&7 (wave*16%8==0).
__global__ __launch_bounds__(256, 1) void k_attn(const int* __restrict__ adj,
    const unsigned short* __restrict__ P,
    const float* __restrict__ f1, const float* __restrict__ f2,
    float* __restrict__ part, float* __restrict__ denp){
  __shared__ __align__(16) int   adjraw[2][64*RK];     // 2 x 32 KB
  __shared__ __align__(16) short Bbuf[2][RK*OUT_F];    // 2 x 32 KB fragment-major
  __shared__ __align__(16) float f2s[KCHUNK];          // 8 KB
  const int tid = threadIdx.x;
  const int wave = tid >> 6, lane = tid & 63;
  const int m = lane & 15, q = lane >> 4;
  const int jc = blockIdx.x;                 // linear id % 4 -> XCD-local P chunk
  const int r0b = blockIdx.y * 64;
  const int jb = jc * KCHUNK;
  const int kb0 = jc * (KCHUNK/32);
  const int r0w = r0b + wave*16;             // this wave's 16 rows

  const float f1v = f1[r0w + m];
  // f2 chunk -> LDS once (8 KB)
  {
    const float4* fsrc = (const float4*)(f2 + jb) + tid*2;
    float4 v0 = fsrc[0], v1 = fsrc[1];
    ((float4*)f2s)[tid*2]     = v0;
    ((float4*)f2s)[tid*2 + 1] = v1;
  }
  f32x4 acc[8];
  #pragma unroll
  for(int c=0;c<8;c++) acc[c] = (f32x4){0,0,0,0};
  float den = 0.f;

  __syncthreads();                           // one-time full drain; f2s visible

  // stage round r into buffer b: 8 adj DMAs + 8 B DMAs (16 total, 64KB)
  auto stage = [&](int r, int b){
    #pragma unroll
    for(int j=0;j<8;j++){
      const int rl = wave*16 + j*2 + (lane>>5);        // row within block (0..63)
      const int g  = (lane>>1) & 15;                   // stored 32B granule
      const int gg = (g & 8) | ((g & 7) ^ (rl & 7));   // global granule
      const int ci = gg*8 + (lane&1)*4;                // int col within row
      gll16(adj + (size_t)(r0b + rl)*N_NODES + jb + r*RK + ci,
            &adjraw[b][(wave*16 + j*2)*RK]);
    }
    #pragma unroll
    for(int j=0;j<8;j++){
      gll16((const char*)P + (((size_t)(kb0 + r*4)) << 13) + wave*8192 + j*1024 + lane*16,
            (char*)Bbuf[b] + wave*8192 + j*1024);
    }
  };

  stage(0, 0);
  for(int rd=0; rd<ROUNDS; rd++){
    const int cur = rd & 1;
    if(rd + 1 < ROUNDS){
      stage(rd + 1, cur ^ 1);
      asm volatile("s_waitcnt vmcnt(16)" ::: "memory");  // prev round's 16 DMAs done
    } else {
      asm volatile("s_waitcnt vmcnt(0)" ::: "memory");   // last round: drain
    }
    __builtin_amdgcn_s_barrier();                         // bufs[cur] ready for all
    #pragma unroll
    for(int s=0;s<4;s++){
      const float* gp = &f2s[rd*RK + s*32 + q*8];         // broadcast per q-group
      float4 g0 = *(const float4*)gp;
      float4 g1 = *(const float4*)(gp + 4);
      const int G = s*4 + q;                              // logical 32B granule
      const int pos = (G & 8) | ((G & 7) ^ (m & 7));      // stored granule
      const int4* ap = (const int4*)&adjraw[cur][(wave*16 + m)*RK + pos*8];
      int4 av0 = ap[0], av1 = ap[1];
      float t0 = f1v + g0.x, t1 = f1v + g0.y, t2 = f1v + g0.z, t3 = f1v + g0.w;
      t0 = t0 > 0.f ? t0 : ALPHA*t0;  t1 = t1 > 0.f ? t1 : ALPHA*t1;
      t2 = t2 > 0.f ? t2 : ALPHA*t2;  t3 = t3 > 0.f ? t3 : ALPHA*t3;
      float w0 = av0.x > 0 ? __expf(t0) : 0.f;
      float w1 = av0.y > 0 ? __expf(t1) : 0.f;
      float w2 = av0.z > 0 ? __expf(t2) : 0.f;
      float w3 = av0.w > 0 ? __expf(t3) : 0.f;
      float t4 = f1v + g1.x, t5 = f1v + g1.y, t6 = f1v + g1.z, t7 = f1v + g1.w;
      t4 = t4 > 0.f ? t4 : ALPHA*t4;  t5 = t5 > 0.f ? t5 : ALPHA*t5;
      t6 = t6 > 0.f ? t6 : ALPHA*t6;  t7 = t7 > 0.f ? t7 : ALPHA*t7;
      float w4 = av1.x > 0 ? __expf(t4) : 0.f;
      float w5 = av1.y > 0 ? __expf(t5) : 0.f;
      float w6 = av1.z > 0 ? __expf(t6) : 0.f;
      float w7 = av1.w > 0 ? __expf(t7) : 0.f;
      uint4 pk;
      pk.x = f2bf(w0) | (f2bf(w1) << 16);
      pk.y = f2bf(w2) | (f2bf(w3) << 16);
      pk.z = f2bf(w4) | (f2bf(w5) << 16);
      pk.w = f2bf(w6) | (f2bf(w7) << 16);
      short8 af = __builtin_bit_cast(short8, pk);
      #pragma unroll
      for(int t=0;t<8;t++) den += bf2f(af[t]);
      #pragma unroll
      for(int c=0;c<8;c++){
        short8 Bf = *(const short8*)&Bbuf[cur][((s*8 + c)*64 + lane)*8];
        acc[c] = __builtin_amdgcn_mfma_f32_16x16x32_bf16(af, Bf, acc[c], 0,0,0);
      }
    }
    asm volatile("s_waitcnt lgkmcnt(0)" ::: "memory");    // LDS reads retired
    __builtin_amdgcn_s_barrier();                         // bufs[cur] free to re-DMA
  }

  // den: lanes m, m+16, m+32, m+48 hold q-partials of row m
  den += __shfl_down(den, 32); den += __shfl_down(den, 16);
  if(lane < 16) denp[(size_t)jc*N_NODES + r0w + lane] = den;
  // C/D layout: col = c*16 + m, row = q*4 + reg (verified)
  float* pp = part + (size_t)jc*N_NODES*OUT_F;
  #pragma unroll
  for(int c=0;c<8;c++){
    #pragma unroll
    for(int reg=0;reg<4;reg++)
      pp[(size_t)(r0w + q*4 + reg)*OUT_F + c*16 + m] = acc[c][reg];
  }
}

// ---------------- K2: out = elu(sum(parts)/sum(dens)), float4 ----------------
__global__ __launch_bounds__(256) void k_out(const float* __restrict__ part,
    const float* __restrict__ denp, float* __restrict__ out){
  const int idx = blockIdx.x*256 + threadIdx.x;    // float4 index
  const int r = idx >> 5;                          // (idx*4) >> 7
  float4 v = {0.f,0.f,0.f,0.f};
  float d = 0.f;
  #pragma unroll
  for(int p=0;p<JC;p++){
    float4 pv = *((const float4*)part + (size_t)p*(N_NODES*OUT_F/4) + idx);
    v.x += pv.x; v.y += pv.y; v.z += pv.z; v.w += pv.w;
    d += denp[(size_t)p*N_NODES + r];
  }
  float4 o;
  o.x = v.x/d; o.y = v.y/d; o.z = v.z/d; o.w = v.w/d;
  o.x = o.x>0.f ? o.x : (__expf(o.x)-1.f);
  o.y = o.y>0.f ? o.y : (__expf(o.y)-1.f);
  o.z = o.z>0.f ? o.z : (__expf(o.z)-1.f);
  o.w = o.w>0.f ? o.w : (__expf(o.w)-1.f);
  *((float4*)out + idx) = o;
}

extern "C" void kernel_launch(void* const* d_in, const int* in_sizes, int n_in,
                              void* d_out, int out_size, void* d_ws, size_t ws_size,
                              hipStream_t stream){
  const float* x   = (const float*)d_in[0];
  const int*   adj = (const int*)d_in[1];
  const float* W   = (const float*)d_in[2];
  const float* a   = (const float*)d_in[3];
  char* ws = (char*)d_ws;
  unsigned short* P = (unsigned short*)ws;                 // 2 MiB
  float* f1         = (float*)(ws + (2u<<20));             // 32 KiB
  float* f2         = (float*)(ws + (2u<<20) + (32u<<10)); // 32 KiB
  float* part       = (float*)(ws + (4u<<20));             // 16 MiB
  float* denp       = (float*)(ws + (20u<<20));            // 128 KiB
  float* out        = (float*)d_out;

  k_hfp<<<512, 256, 0, stream>>>(x, W, a, P, f1, f2);
  k_attn<<<dim3(JC,128), 256, 0, stream>>>(adj, P, f1, f2, part, denp);
  k_out<<<(N_NODES*OUT_F)/4/256, 256, 0, stream>>>(part, denp, out);
}

// Round 10
// 417.943 us; speedup vs baseline: 1.0389x; 1.0389x over previous
//
#include <hip/hip_runtime.h>

#define N_NODES 8192
#define IN_F 256
#define OUT_F 128
#define ALPHA 0.5f
#define JC 4
#define KCHUNK 2048            // N_NODES / JC
#define RK 128                 // k-window per round
#define ROUNDS 16              // KCHUNK / RK

using short8 = __attribute__((ext_vector_type(8))) short;
using f32x4  = __attribute__((ext_vector_type(4))) float;

__device__ __forceinline__ unsigned int f2bf(float f){
  unsigned int u = __float_as_uint(f);
  u += 0x7fffu + ((u >> 16) & 1u);   // RNE
  return u >> 16;
}
__device__ __forceinline__ float bf2f(short s){
  return __uint_as_float(((unsigned int)(unsigned short)s) << 16);
}
__device__ __forceinline__ void gll16(const void* g, void* l){
  __builtin_amdgcn_global_load_lds(
      (const __attribute__((address_space(1))) void*)g,
      (__attribute__((address_space(3))) void*)l, 16, 0, 0);
}

// ---------------- K0: fused  h = x@W  ->  {f1, f2, P(bf16 frag-major)} -----
__global__ __launch_bounds__(256) void k_hfp(const float* __restrict__ x,
                                             const float* __restrict__ W,
                                             const float* __restrict__ a,
                                             unsigned short* __restrict__ P,
                                             float* __restrict__ f1,
                                             float* __restrict__ f2){
  __shared__ float xs[16*IN_F];            // 16 KB; reused as hs[16][132]
  const int tid = threadIdx.x;
  const int bx = blockIdx.x;
  const int r0 = bx * 16;
  const float4* xg = (const float4*)(x + (size_t)r0*IN_F);
  float4* xl = (float4*)xs;
  #pragma unroll
  for(int i=0;i<4;i++) xl[tid + i*256] = xg[tid + i*256];
  __syncthreads();
  const int wave = tid >> 6, lane = tid & 63;
  float2 acc[4];
  #pragma unroll
  for(int j=0;j<4;j++){ acc[j].x = 0.f; acc[j].y = 0.f; }
  const float2* Wp = (const float2*)W;
  for(int k4=0;k4<IN_F;k4+=4){
    float4 xq[4];
    #pragma unroll
    for(int j=0;j<4;j++) xq[j] = *(const float4*)&xs[(wave*4+j)*IN_F + k4];
    #pragma unroll
    for(int kk=0;kk<4;kk++){
      float2 wv = Wp[(size_t)(k4+kk)*64 + lane];
      #pragma unroll
      for(int j=0;j<4;j++){
        float xv = kk==0?xq[j].x : kk==1?xq[j].y : kk==2?xq[j].z : xq[j].w;
        acc[j].x += xv*wv.x; acc[j].y += xv*wv.y;
      }
    }
  }
  // ---- f1 = h@a1, f2 = h@a2 from fp32 accumulators ----
  float2 av1 = ((const float2*)a)[lane];
  float2 av2 = ((const float2*)(a + OUT_F))[lane];
  #pragma unroll
  for(int j=0;j<4;j++){
    float s1 = acc[j].x*av1.x + acc[j].y*av1.y;
    float s2 = acc[j].x*av2.x + acc[j].y*av2.y;
    #pragma unroll
    for(int off=32; off; off>>=1){
      s1 += __shfl_down(s1, off);
      s2 += __shfl_down(s2, off);
    }
    if(lane == 0){ f1[r0 + wave*4 + j] = s1; f2[r0 + wave*4 + j] = s2; }
  }
  // ---- pack bf16 fragment-major into P via LDS re-stage ----
  // P short idx ((kb*8+c)*64 + q*16 + n)*8 + t = bf16(h[kb*32+q*8+t][c*16+n])
  __syncthreads();                         // all waves done reading xs
  #pragma unroll
  for(int j=0;j<4;j++) *(float2*)&xs[(wave*4+j)*132 + lane*2] = acc[j];
  __syncthreads();
  const int kb = bx >> 1, half = bx & 1;   // this block = rows [r0, r0+16) = half of kb's 32
  const int c = tid >> 5, ql = (tid >> 4) & 1, n = tid & 15;
  short8 v;
  #pragma unroll
  for(int t=0;t<8;t++) v[t] = (short)f2bf(xs[(ql*8+t)*132 + c*16 + n]);
  *(short8*)(P + ((size_t)((kb*8 + c)*64 + half*32 + ql*16 + n))*8) = v;
}

// ---------------- K1: barrier-free per-wave DMA pipeline -------------------
// grid (JC=4, 128) x 256 thr, 2 blocks/CU, LDS 72 KB.
// Each wave owns 16 rows; its adj tile is WAVE-PRIVATE in LDS -> no
// s_barrier anywhere in the loop (waves self-stagger; no convoy effect;
// the per-CU HBM stream stays continuous).
// Per round, per wave (vmem queue order is the correctness invariant):
//   [32 B-frag loads from L2-resident P -> registers]   (B never behind adj)
//   [compiler fence]
//   [8 global_load_lds: round rd+1 adj -> private dbuf region]
//   s_waitcnt vmcnt(8): drains B (needed now) + round-rd DMAs (issued a
//   full round ago, already landed); the 8 fresh DMAs stay in flight
//   through the whole compute phase. Then 4 substeps of ds_read->exp->MFMA.
// In-order vmcnt retirement is respected: no B-wait can drain adj DMAs.
__global__ __launch_bounds__(256, 2) void k_attn(const int* __restrict__ adj,
    const unsigned short* __restrict__ P,
    const float* __restrict__ f1, const float* __restrict__ f2,
    float* __restrict__ part, float* __restrict__ denp){
  __shared__ __align__(16) int   adjraw[2][64*RK];     // 2 x 32 KB, linear [row][k]
  __shared__ __align__(16) float f2s[KCHUNK];          // 8 KB
  const int tid = threadIdx.x;
  const int wave = tid >> 6, lane = tid & 63;
  const int m = lane & 15, q = lane >> 4;
  const int jc = blockIdx.x;                 // linear id % 4 -> XCD-local P chunk
  const int r0b = blockIdx.y * 64;
  const int jb = jc * KCHUNK;
  const int kb0 = jc * (KCHUNK/32);
  const int r0w = r0b + wave*16;             // this wave's 16 rows

  const float f1v = f1[r0w + m];
  // f2 chunk -> LDS once (8 KB)
  {
    const float4* fsrc = (const float4*)(f2 + jb) + tid*2;
    float4 v0 = fsrc[0], v1 = fsrc[1];
    ((float4*)f2s)[tid*2]     = v0;
    ((float4*)f2s)[tid*2 + 1] = v1;
  }
  f32x4 acc[8];
  #pragma unroll
  for(int c=0;c<8;c++) acc[c] = (f32x4){0,0,0,0};
  float den = 0.f;

  __syncthreads();                           // one-time: f2s visible

  // stage round r's adj rows (wave-private) into buffer b: 8 DMAs, linear
  auto stage = [&](int r, int b){
    #pragma unroll
    for(int j=0;j<8;j++){
      const int rl = wave*16 + j*2 + (lane>>5);        // row within block
      gll16(adj + (size_t)(r0b + rl)*N_NODES + jb + r*RK + (lane&31)*4,
            &adjraw[b][(wave*16 + j*2)*RK]);
    }
  };

  stage(0, 0);
  const short8* P8 = (const short8*)P;
  for(int rd=0; rd<ROUNDS; rd++){
    const int cur = rd & 1;
    // ---- B-frags for this round: 32 x 16B from L2 (before any adj DMA) ----
    short8 bf[4][8];
    #pragma unroll
    for(int s=0;s<4;s++){
      #pragma unroll
      for(int c=0;c<8;c++)
        bf[s][c] = P8[(((size_t)(kb0 + rd*4 + s)*8 + c)*64 + lane)];
    }
    asm volatile("" ::: "memory");           // pin B loads above the DMAs
    // ---- prefetch round rd+1 adj (stays in flight through compute) ----
    if(rd + 1 < ROUNDS){
      stage(rd + 1, cur ^ 1);
      asm volatile("s_waitcnt vmcnt(8)" ::: "memory");  // B + round-rd DMAs done
    } else {
      asm volatile("s_waitcnt vmcnt(0)" ::: "memory");  // last round
    }
    // ---- compute: 4 substeps, wave-private adjraw reads, no barriers ----
    #pragma unroll
    for(int s=0;s<4;s++){
      const float* gp = &f2s[rd*RK + s*32 + q*8];       // broadcast per q-group
      float4 g0 = *(const float4*)gp;
      float4 g1 = *(const float4*)(gp + 4);
      const int4* ap = (const int4*)&adjraw[cur][(wave*16 + m)*RK + (s*4 + q)*8];
      int4 av0 = ap[0], av1 = ap[1];
      float t0 = f1v + g0.x, t1 = f1v + g0.y, t2 = f1v + g0.z, t3 = f1v + g0.w;
      t0 = t0 > 0.f ? t0 : ALPHA*t0;  t1 = t1 > 0.f ? t1 : ALPHA*t1;
      t2 = t2 > 0.f ? t2 : ALPHA*t2;  t3 = t3 > 0.f ? t3 : ALPHA*t3;
      float w0 = av0.x > 0 ? __expf(t0) : 0.f;
      float w1 = av0.y > 0 ? __expf(t1) : 0.f;
      float w2 = av0.z > 0 ? __expf(t2) : 0.f;
      float w3 = av0.w > 0 ? __expf(t3) : 0.f;
      float t4 = f1v + g1.x, t5 = f1v + g1.y, t6 = f1v + g1.z, t7 = f1v + g1.w;
      t4 = t4 > 0.f ? t4 : ALPHA*t4;  t5 = t5 > 0.f ? t5 : ALPHA*t5;
      t6 = t6 > 0.f ? t6 : ALPHA*t6;  t7 = t7 > 0.f ? t7 : ALPHA*t7;
      float w4 = av1.x > 0 ? __expf(t4) : 0.f;
      float w5 = av1.y > 0 ? __expf(t5) : 0.f;
      float w6 = av1.z > 0 ? __expf(t6) : 0.f;
      float w7 = av1.w > 0 ? __expf(t7) : 0.f;
      uint4 pk;
      pk.x = f2bf(w0) | (f2bf(w1) << 16);
      pk.y = f2bf(w2) | (f2bf(w3) << 16);
      pk.z = f2bf(w4) | (f2bf(w5) << 16);
      pk.w = f2bf(w6) | (f2bf(w7) << 16);
      short8 af = __builtin_bit_cast(short8, pk);
      #pragma unroll
      for(int t=0;t<8;t++) den += bf2f(af[t]);
      #pragma unroll
      for(int c=0;c<8;c++)
        acc[c] = __builtin_amdgcn_mfma_f32_16x16x32_bf16(af, bf[s][c], acc[c], 0,0,0);
    }
  }

  // den: lanes m, m+16, m+32, m+48 hold q-partials of row m
  den += __shfl_down(den, 32); den += __shfl_down(den, 16);
  if(lane < 16) denp[(size_t)jc*N_NODES + r0w + lane] = den;
  // C/D layout: col = c*16 + m, row = q*4 + reg (verified)
  float* pp = part + (size_t)jc*N_NODES*OUT_F;
  #pragma unroll
  for(int c=0;c<8;c++){
    #pragma unroll
    for(int reg=0;reg<4;reg++)
      pp[(size_t)(r0w + q*4 + reg)*OUT_F + c*16 + m] = acc[c][reg];
  }
}

// ---------------- K2: out = elu(sum(parts)/sum(dens)), float4 ----------------
__global__ __launch_bounds__(256) void k_out(const float* __restrict__ part,
    const float* __restrict__ denp, float* __restrict__ out){
  const int idx = blockIdx.x*256 + threadIdx.x;    // float4 index
  const int r = idx >> 5;                          // (idx*4) >> 7
  float4 v = {0.f,0.f,0.f,0.f};
  float d = 0.f;
  #pragma unroll
  for(int p=0;p<JC;p++){
    float4 pv = *((const float4*)part + (size_t)p*(N_NODES*OUT_F/4) + idx);
    v.x += pv.x; v.y += pv.y; v.z += pv.z; v.w += pv.w;
    d += denp[(size_t)p*N_NODES + r];
  }
  float4 o;
  o.x = v.x/d; o.y = v.y/d; o.z = v.z/d; o.w = v.w/d;
  o.x = o.x>0.f ? o.x : (__expf(o.x)-1.f);
  o.y = o.y>0.f ? o.y : (__expf(o.y)-1.f);
  o.z = o.z>0.f ? o.z : (__expf(o.z)-1.f);
  o.w = o.w>0.f ? o.w : (__expf(o.w)-1.f);
  *((float4*)out + idx) = o;
}

extern "C" void kernel_launch(void* const* d_in, const int* in_sizes, int n_in,
                              void* d_out, int out_size, void* d_ws, size_t ws_size,
                              hipStream_t stream){
  const float* x   = (const float*)d_in[0];
  const int*   adj = (const int*)d_in[1];
  const float* W   = (const float*)d_in[2];
  const float* a   = (const float*)d_in[3];
  char* ws = (char*)d_ws;
  unsigned short* P = (unsigned short*)ws;                 // 2 MiB
  float* f1         = (float*)(ws + (2u<<20));             // 32 KiB
  float* f2         = (float*)(ws + (2u<<20) + (32u<<10)); // 32 KiB
  float* part       = (float*)(ws + (4u<<20));             // 16 MiB
  float* denp       = (float*)(ws + (20u<<20));            // 128 KiB
  float* out        = (float*)d_out;

  k_hfp<<<512, 256, 0, stream>>>(x, W, a, P, f1, f2);
  k_attn<<<dim3(JC,128), 256, 0, stream>>>(adj, P, f1, f2, part, denp);
  k_out<<<(N_NODES*OUT_F)/4/256, 256, 0, stream>>>(part, denp, out);
}